// Round 7
// baseline (156.252 us; speedup 1.0000x reference)
//
#include <hip/hip_runtime.h>
#include <cmath>

#define S_SEQ 4096
#define HD 1024
#define NG 3072           // 3*H
#define CHR 32            // rows per scan chunk
#define NCH 128           // chunks (CHR*NCH = 4096)
#define NT1 32            // GEMM1 K-tiles of 64 (K=2048)

typedef _Float16 half8_t __attribute__((ext_vector_type(8)));
typedef _Float16 half4_t __attribute__((ext_vector_type(4)));
typedef float f32x4_t __attribute__((ext_vector_type(4)));

__device__ __forceinline__ void gload_lds16(const void* g, void* l) {
  __builtin_amdgcn_global_load_lds(
      (const __attribute__((address_space(1))) void*)g,
      (__attribute__((address_space(3))) void*)l, 16, 0, 0);
}

__device__ __forceinline__ float sigmoidf_(float x) {
  return 1.f / (1.f + __expf(-x));
}
__device__ __forceinline__ float tanhf_(float x) {
  return 1.f - 2.f / (__expf(2.f * x) + 1.f);
}

// ---------------- prep: weight conversion + vectorized scan_x --------------
#define CONV_BLOCKS 7168
__global__ void prep(const float* __restrict__ W1, const float* __restrict__ W2,
                     _Float16* __restrict__ w1h, _Float16* __restrict__ w2h,
                     const float* __restrict__ x, _Float16* __restrict__ A,
                     _Float16* __restrict__ xsum) {
  const int bid = blockIdx.x;
  if (bid < CONV_BLOCKS) {
    const int n1 = NG * 2048 / 4;
    int i = bid * 256 + threadIdx.x;
    const float* src = (i < n1) ? (W1 + (size_t)i * 4)
                                : (W2 + (size_t)(i - n1) * 4);
    _Float16* dst = (i < n1) ? (w1h + (size_t)i * 4)
                             : (w2h + (size_t)(i - n1) * 4);
    float4 v = *(const float4*)src;
    half4_t h;
    h[0] = (_Float16)v.x; h[1] = (_Float16)v.y;
    h[2] = (_Float16)v.z; h[3] = (_Float16)v.w;
    *(half4_t*)dst = h;
  } else {
    const int c = bid - CONV_BLOCKS;          // chunk 0..127
    const int j = threadIdx.x * 4;            // 4 columns per thread
    const int t0 = c * CHR;
    float4 run = make_float4(0.f, 0.f, 0.f, 0.f);
    for (int t = t0; t < t0 + CHR; ++t) {
      float4 v = *(const float4*)&x[(size_t)t * HD + j];
      half4_t hx, hs;
      hx[0] = (_Float16)v.x;   hx[1] = (_Float16)v.y;
      hx[2] = (_Float16)v.z;   hx[3] = (_Float16)v.w;
      hs[0] = (_Float16)run.x; hs[1] = (_Float16)run.y;
      hs[2] = (_Float16)run.z; hs[3] = (_Float16)run.w;
      *(half4_t*)&A[(size_t)t * 2048 + j] = hx;
      *(half4_t*)&A[(size_t)t * 2048 + 1024 + j] = hs;
      run.x += v.x; run.y += v.y; run.z += v.z; run.w += v.w;
    }
    half4_t hxs;
    hxs[0] = (_Float16)run.x; hxs[1] = (_Float16)run.y;
    hxs[2] = (_Float16)run.z; hxs[3] = (_Float16)run.w;
    *(half4_t*)&xsum[(size_t)c * HD + j] = hxs;
  }
}

// ---------------- exclusive scan over 4 K-split partials + b1 --------------
__global__ void scan_part(const float* __restrict__ praw,
                          const float* __restrict__ b1,
                          float* __restrict__ pout) {
  int j = blockIdx.x * 256 + threadIdx.x;   // 0..3071
  const size_t SP = (size_t)NCH * NG;
  float run = b1[j];
  for (int c = 0; c < NCH; c += 8) {
    float v[8];
#pragma unroll
    for (int u = 0; u < 8; ++u) {
      size_t i0 = (size_t)(c + u) * NG + j;
      v[u] = (praw[i0] + praw[i0 + SP]) + (praw[i0 + 2 * SP] + praw[i0 + 3 * SP]);
    }
#pragma unroll
    for (int u = 0; u < 8; ++u) {
      pout[(size_t)(c + u) * NG + j] = run;
      run += v[u];
    }
  }
}

// ---------------- partGEMM: praw4[z] = xsum @ W1b^T over K window z --------
__global__ __launch_bounds__(256, 2)
void gemm_part(const _Float16* __restrict__ A, const _Float16* __restrict__ B,
               float* __restrict__ C) {
  __shared__ _Float16 As[128 * 32];
  __shared__ _Float16 Bs[128 * 32];

  const int tid = threadIdx.x;
  const int lane = tid & 63;
  const int wid = tid >> 6;
  const int wr = wid >> 1;
  const int wc = wid & 1;

  const int n0 = blockIdx.x * 128;
  const int koff = blockIdx.z * 256;

  const int srow = lane >> 2;
  const int scol = (lane & 3) << 3;

  const _Float16* gA = A + (size_t)(wid * 32 + srow) * 1024 + koff + scol;
  const _Float16* gB = B + (size_t)(n0 + wid * 32 + srow) * 2048 + koff + scol;
  _Float16* lA = As + (wid * 32) * 32;
  _Float16* lB = Bs + (wid * 32) * 32;

  f32x4_t acc[4][4] = {};

  const int fr = lane & 15;
  const int fk = (lane >> 4) << 3;

  for (int kk = 0; kk < 256; kk += 32) {
    gload_lds16(gA + kk,                    lA);
    gload_lds16(gA + kk + (size_t)16*1024,  lA + 16 * 32);
    gload_lds16(gB + kk,                    lB);
    gload_lds16(gB + kk + (size_t)16*2048,  lB + 16 * 32);
    __syncthreads();

    half8_t af[4], bf[4];
#pragma unroll
    for (int m = 0; m < 4; ++m)
      af[m] = *(const half8_t*)&As[(wr * 64 + m * 16 + fr) * 32 + fk];
#pragma unroll
    for (int n = 0; n < 4; ++n)
      bf[n] = *(const half8_t*)&Bs[(wc * 64 + n * 16 + fr) * 32 + fk];
#pragma unroll
    for (int m = 0; m < 4; ++m)
#pragma unroll
      for (int n = 0; n < 4; ++n)
        acc[m][n] = __builtin_amdgcn_mfma_f32_16x16x32_f16(af[m], bf[n],
                                                           acc[m][n], 0, 0, 0);
    __syncthreads();
  }

  float* Cz = C + (size_t)blockIdx.z * NCH * NG;
  const int crow = wr * 64 + ((lane >> 4) << 2);
  const int ccol = n0 + wc * 64 + fr;
#pragma unroll
  for (int m = 0; m < 4; ++m)
#pragma unroll
    for (int n = 0; n < 4; ++n) {
      const int col = ccol + n * 16;
#pragma unroll
      for (int r = 0; r < 4; ++r)
        Cz[(size_t)(crow + m * 16 + r) * NG + col] = acc[m][n][r];
    }
}

// ---------------- GEMM2: triple-buffered counted-vmcnt (proven R6) ---------
#define BARX __builtin_amdgcn_s_barrier()
#define PR1 __builtin_amdgcn_s_setprio(1)
#define PR0 __builtin_amdgcn_s_setprio(0)
#define VM4 asm volatile("s_waitcnt vmcnt(4)" ::: "memory")
#define VM6 asm volatile("s_waitcnt vmcnt(6)" ::: "memory")
#define LGKM0 asm volatile("s_waitcnt lgkmcnt(0)" ::: "memory")
#define SB0 __builtin_amdgcn_sched_barrier(0)

template <int NTILE>
__global__ __launch_bounds__(256, 3)
void gemm2_t3(const _Float16* __restrict__ A, const _Float16* __restrict__ B,
              int N, float* __restrict__ outf,
              const float* __restrict__ bias, const _Float16* __restrict__ mulh) {
  constexpr int KS = NTILE * 32;
  __shared__ __align__(16) _Float16 sA[3][128 * 32];
  __shared__ __align__(16) _Float16 sB[3][128 * 32];

  const int tid = threadIdx.x;
  const int l = tid & 63;
  const int wid = tid >> 6;
  const int wr = wid >> 1;
  const int wc = wid & 1;
  const int m0 = blockIdx.y * 128;
  const int n0 = blockIdx.x * 128;

  const int srow = tid >> 2;
  const int schunk = (tid & 3) ^ ((tid >> 3) & 3);
  const _Float16* gA = A + (size_t)(m0 + srow) * KS + schunk * 8;
  const _Float16* gB = B + (size_t)(n0 + srow) * KS + schunk * 8;
  const int ldst = tid * 8;

#define STG(bn, kt) do {                                              \
    const int kk_ = (kt) * 32;                                        \
    gload_lds16(gA + kk_,           &sA[bn][ldst]);                   \
    gload_lds16(gA + kk_ + 64 * KS, &sA[bn][2048 + ldst]);            \
    gload_lds16(gB + kk_,           &sB[bn][ldst]);                   \
    gload_lds16(gB + kk_ + 64 * KS, &sB[bn][2048 + ldst]);            \
  } while (0)

  const int fr = l & 15;
  const int kidx = (((l >> 4) ^ ((l >> 1) & 3)) << 3);

  f32x4_t acc[4][4] = {};

#define BODY(kt, bc, bn) do {                                         \
    int ks_ = (kt) + 2; if (ks_ > NTILE - 1) ks_ = NTILE - 1;         \
    STG(bn, ks_);                                                     \
    half8_t af[4], bf[4];                                             \
    _Pragma("unroll")                                                 \
    for (int m = 0; m < 4; ++m)                                       \
      af[m] = *(const half8_t*)&sA[bc][(wr*64 + m*16 + fr)*32 + kidx];\
    _Pragma("unroll")                                                 \
    for (int n = 0; n < 4; ++n)                                       \
      bf[n] = *(const half8_t*)&sB[bc][(wc*64 + n*16 + fr)*32 + kidx];\
    PR1;                                                              \
    _Pragma("unroll")                                                 \
    for (int m = 0; m < 4; ++m)                                       \
      _Pragma("unroll")                                               \
      for (int n = 0; n < 4; ++n)                                     \
        acc[m][n] = __builtin_amdgcn_mfma_f32_16x16x32_f16(           \
            af[m], bf[n], acc[m][n], 0, 0, 0);                        \
    PR0;                                                              \
    VM4; BARX;                                                        \
  } while (0)

  STG(0, 0);
  STG(1, 1);
  VM4; BARX;

#pragma unroll 1
  for (int t3 = 0; t3 < NTILE / 3; ++t3) {
    const int kt = t3 * 3;
    BODY(kt,     0, 2);
    BODY(kt + 1, 1, 0);
    BODY(kt + 2, 2, 1);
  }
  if constexpr (NTILE % 3 >= 1) BODY(NTILE - NTILE % 3,     0, 2);
  if constexpr (NTILE % 3 >= 2) BODY(NTILE - NTILE % 3 + 1, 1, 0);

  const int crow = m0 + wr * 64 + ((l >> 4) << 2);
  const int ccol = n0 + wc * 64 + fr;
#pragma unroll
  for (int m = 0; m < 4; ++m)
#pragma unroll
    for (int n = 0; n < 4; ++n) {
      const int col = ccol + n * 16;
#pragma unroll
      for (int r = 0; r < 4; ++r) {
        const int row = crow + m * 16 + r;
        size_t idx = (size_t)row * N + col;
        outf[idx] = (acc[m][n][r] + bias[col]) * (float)mulh[idx];
      }
    }
#undef STG
#undef BODY
}

// ---------------- GEMM1: 256x256, faithful m201 8-phase --------------------
// gates[4096,3072] = Ah[4096,2048] @ w1h[3072,2048]^T + part[(row>>5)][col]
// Staging halves by READ-timing stripes:
//   A half h: 64-row stripes {h*64, 128+h*64}  (alo reads h=0 @q0, ahi h=1 @q2)
//   B half h: 32-row stripes {h*32 + k*64}     (blo reads h=0 @q0, bhi h=1 @q1)
// Per phase: 1 half staged (2 gloads/thread). vmcnt(6) at q3 only.
__global__ __launch_bounds__(512)
void gemm1_8ph(const _Float16* __restrict__ A, const _Float16* __restrict__ B,
               const float* __restrict__ part, _Float16* __restrict__ igb,
               float* __restrict__ out0, _Float16* __restrict__ th) {
  __shared__ __align__(16) _Float16 sA[2][256 * 64];
  __shared__ __align__(16) _Float16 sB[2][256 * 64];

  const int tid = threadIdx.x;
  const int l = tid & 63;
  const int w = tid >> 6;          // 0..7
  const int wr = w >> 2;           // 0..1  (M half)
  const int wc = w & 3;            // 0..3  (N quarter)

  // bijective XCD swizzle: 192 blocks
  const int id = blockIdx.x;
  const int swz = (id & 7) * 24 + (id >> 3);
  const int bx = swz % 12;
  const int by = swz / 12;
  const int m0 = by * 256;
  const int n0 = bx * 256;

  // staging bases (pre-swizzled source, linear LDS dest)
  const int lr = l >> 3;                       // row-in-octet
  const int lcs = ((l & 7) ^ lr) << 3;         // pre-swizzled chunk (halfs)
  const _Float16* gA0 =
      A + (size_t)(m0 + (w >> 2) * 128 + (w & 3) * 16 + lr) * 2048 + lcs;
  const _Float16* gB0 =
      B + (size_t)(n0 + (w >> 1) * 64 + (w & 1) * 16 + lr) * 2048 + lcs;
  const int dsoA = ((w >> 2) * 128 + (w & 3) * 16) * 64;
  const int dsoB = ((w >> 1) * 64 + (w & 1) * 16) * 64;

#define STG_A(bb, h, tt) do {                                          \
    const _Float16* gs_ = gA0 + (size_t)(h) * 64 * 2048 + (tt) * 64;   \
    _Float16* ds_ = &sA[bb][dsoA + (h) * 4096];                        \
    gload_lds16(gs_, ds_);                                             \
    gload_lds16(gs_ + 8 * 2048, ds_ + 512);                            \
  } while (0)
#define STG_B(bb, h, tt) do {                                          \
    const _Float16* gs_ = gB0 + (size_t)(h) * 32 * 2048 + (tt) * 64;   \
    _Float16* ds_ = &sB[bb][dsoB + (h) * 2048];                        \
    gload_lds16(gs_, ds_);                                             \
    gload_lds16(gs_ + 8 * 2048, ds_ + 512);                            \
  } while (0)

  const int sw = (l & 7) << 3;
  const int k0 = (l >> 4) << 3;

#define RDA(dst, mb, kh, bb)                                                  \
    dst = *(const half8_t*)&sA[bb][(((wr * 128 + (mb) * 16 + (l & 15)) * 64)  \
                                    + k0 + (kh) * 32) ^ sw];
#define RDB(dst, nb, kh, bb)                                                  \
    dst = *(const half8_t*)&sB[bb][(((wc * 64 + (nb) * 16 + (l & 15)) * 64)   \
                                    + k0 + (kh) * 32) ^ sw];

  f32x4_t acc[2][2][4][2] = {};

#define MMQ(MH, NH, AF, BF) do {                                      \
    _Pragma("unroll")                                                 \
    for (int m = 0; m < 4; ++m)                                       \
      _Pragma("unroll")                                               \
      for (int n = 0; n < 2; ++n) {                                   \
        acc[MH][NH][m][n] = __builtin_amdgcn_mfma_f32_16x16x32_f16(   \
            AF[m][0], BF[n][0], acc[MH][NH][m][n], 0, 0, 0);          \
        acc[MH][NH][m][n] = __builtin_amdgcn_mfma_f32_16x16x32_f16(   \
            AF[m][1], BF[n][1], acc[MH][NH][m][n], 0, 0, 0);          \
      }                                                               \
  } while (0)

  half8_t alo[4][2], ahi[4][2], blo[2][2], bhi[2][2];

  // prologue: tile0 all 4 halves + tile1 {A0,B0,B1}  (14 loads)
  STG_A(0, 0, 0); STG_B(0, 0, 0); STG_B(0, 1, 0); STG_A(0, 1, 0);
  STG_A(1, 0, 1); STG_B(1, 0, 1); STG_B(1, 1, 1);
  VM6; BARX;

#define TILE(T, BUF) do {                                             \
    const int t1_ = ((T) + 1 < NT1) ? (T) + 1 : NT1 - 1;              \
    const int t2_ = ((T) + 2 < NT1) ? (T) + 2 : NT1 - 1;              \
    /* q0: read alo+blo; stage A-hi(t+1) into other buf */            \
    _Pragma("unroll")                                                 \
    for (int m = 0; m < 4; ++m) {                                     \
      RDA(alo[m][0], m, 0, BUF); RDA(alo[m][1], m, 1, BUF);           \
    }                                                                 \
    _Pragma("unroll")                                                 \
    for (int n = 0; n < 2; ++n) {                                     \
      RDB(blo[n][0], n, 0, BUF); RDB(blo[n][1], n, 1, BUF);           \
    }                                                                 \
    STG_A((BUF) ^ 1, 1, t1_);                                         \
    SB0; BARX; LGKM0; SB0;                                            \
    PR1; MMQ(0, 0, alo, blo); PR0; BARX;                              \
    /* q1: read bhi; stage A-lo(t+2) into this buf (read @q0) */      \
    _Pragma("unroll")                                                 \
    for (int n = 0; n < 2; ++n) {                                     \
      RDB(bhi[n][0], 2 + n, 0, BUF); RDB(bhi[n][1], 2 + n, 1, BUF);   \
    }                                                                 \
    STG_A(BUF, 0, t2_);                                               \
    SB0; BARX; LGKM0; SB0;                                            \
    PR1; MMQ(0, 1, alo, bhi); PR0; BARX;                              \
    /* q2: read ahi; stage B-lo(t+2) (read @q0) */                    \
    _Pragma("unroll")                                                 \
    for (int m = 0; m < 4; ++m) {                                     \
      RDA(ahi[m][0], 4 + m, 0, BUF); RDA(ahi[m][1], 4 + m, 1, BUF);   \
    }                                                                 \
    STG_B(BUF, 0, t2_);                                               \
    SB0; BARX; LGKM0; SB0;                                            \
    PR1; MMQ(1, 0, ahi, blo); PR0; BARX;                              \
    /* q3: stage B-hi(t+2) (read @q1); counted drain */               \
    STG_B(BUF, 1, t2_);                                               \
    BARX;                                                             \
    PR1; MMQ(1, 1, ahi, bhi); PR0; VM6; BARX;                         \
  } while (0)

#pragma unroll 1
  for (int t = 0; t < NT1; t += 2) {
    TILE(t, 0);
    TILE(t + 1, 1);
  }

  // ---- epilogue: block-uniform gate region ----
  const int region = n0 >> 10;               // 0=ig, 1=fg, 2=h
  const int cb = n0 & 1023;
#pragma unroll
  for (int mh = 0; mh < 2; ++mh)
#pragma unroll
    for (int m = 0; m < 4; ++m) {
      const int rbase = m0 + wr * 128 + mh * 64 + m * 16 + ((l >> 4) << 2);
#pragma unroll
      for (int r = 0; r < 4; ++r) {
        const int grow = rbase + r;
        const float* prow = part + (size_t)(grow >> 5) * NG + n0;
#pragma unroll
        for (int nh = 0; nh < 2; ++nh)
#pragma unroll
          for (int n = 0; n < 2; ++n) {
            const int lc = wc * 64 + nh * 32 + n * 16 + (l & 15);
            const float g = acc[mh][nh][m][n][r] + prow[lc];
            const size_t oi = (size_t)grow * HD + cb + lc;
            if (region == 0)      igb[oi] = (_Float16)sigmoidf_(g);
            else if (region == 1) out0[oi] = sigmoidf_(g);
            else                  th[oi] = (_Float16)tanhf_(g);
          }
      }
    }
#undef STG_A
#undef STG_B
#undef RDA
#undef RDB
#undef MMQ
#undef TILE
}

// ---------------- launch ----------------
extern "C" void kernel_launch(void* const* d_in, const int* in_sizes, int n_in,
                              void* d_out, int out_size, void* d_ws, size_t ws_size,
                              hipStream_t stream) {
  const float* x  = (const float*)d_in[0];
  const float* W1 = (const float*)d_in[1];
  const float* b1 = (const float*)d_in[2];
  const float* W2 = (const float*)d_in[3];
  const float* b2 = (const float*)d_in[4];
  float* out0 = (float*)d_out;                          // fg [4096][1024]
  float* out1 = out0 + (size_t)S_SEQ * HD;              // hr [4096][1024]

  char* ws = (char*)d_ws;
  _Float16* Ah    = (_Float16*)(ws);                        // 16 MiB [4096][2048]
  _Float16* w1h   = (_Float16*)(ws + ((size_t)16 << 20));   // 12 MiB [3072][2048]
  _Float16* w2h   = (_Float16*)(ws + ((size_t)28 << 20));   //  2 MiB [1024][1024]
  _Float16* xsumh = (_Float16*)(ws + ((size_t)30 << 20));   // .25MiB [128][1024]
  float*    praw4 = (float*)   (ws + ((size_t)31 << 20));   //  6 MiB [4][128][3072]
  float*    pout  = (float*)   (ws + ((size_t)37 << 20));   // 1.5MiB [128][3072]
  _Float16* igb   = (_Float16*)(ws + ((size_t)39 << 20));   //  8 MiB [4096][1024]
  _Float16* th    = (_Float16*)(ws + ((size_t)47 << 20));   //  8 MiB [4096][1024]

  prep<<<dim3(CONV_BLOCKS + 128), dim3(256), 0, stream>>>(
      W1, W2, w1h, w2h, x, Ah, xsumh);

  gemm_part<<<dim3(NG / 128, 1, 4), dim3(256), 0, stream>>>(
      xsumh, w1h + 1024, praw4);

  scan_part<<<dim3(NG / 256), dim3(256), 0, stream>>>(praw4, b1, pout);

  gemm1_8ph<<<dim3(192), dim3(512), 0, stream>>>(
      Ah, w1h, pout, igb, out0, th);

  gemm2_t3<32><<<dim3(HD / 128, S_SEQ / 128), dim3(256), 0, stream>>>(
      th, w2h, HD, out1, b2, igb);
}

// Round 8
// 149.148 us; speedup vs baseline: 1.0476x; 1.0476x over previous
//
#include <hip/hip_runtime.h>
#include <cmath>

#define S_SEQ 4096
#define HD 1024
#define NG 3072           // 3*H
#define CHR 32            // rows per scan chunk
#define NCH 128           // chunks (CHR*NCH = 4096)
#define NZ 8              // gemm_part K slices

typedef _Float16 half8_t __attribute__((ext_vector_type(8)));
typedef _Float16 half4_t __attribute__((ext_vector_type(4)));
typedef float f32x4_t __attribute__((ext_vector_type(4)));

__device__ __forceinline__ void gload_lds16(const void* g, void* l) {
  __builtin_amdgcn_global_load_lds(
      (const __attribute__((address_space(1))) void*)g,
      (__attribute__((address_space(3))) void*)l, 16, 0, 0);
}

__device__ __forceinline__ float sigmoidf_(float x) {
  return 1.f / (1.f + __expf(-x));
}
__device__ __forceinline__ float tanhf_(float x) {
  return 1.f - 2.f / (__expf(2.f * x) + 1.f);
}

// ---------------- prep: weight conversion + vectorized scan_x --------------
#define CONV_BLOCKS 7168
__global__ void prep(const float* __restrict__ W1, const float* __restrict__ W2,
                     _Float16* __restrict__ w1h, _Float16* __restrict__ w2h,
                     const float* __restrict__ x, _Float16* __restrict__ A,
                     _Float16* __restrict__ xsum) {
  const int bid = blockIdx.x;
  if (bid < CONV_BLOCKS) {
    const int n1 = NG * 2048 / 4;
    int i = bid * 256 + threadIdx.x;
    const float* src = (i < n1) ? (W1 + (size_t)i * 4)
                                : (W2 + (size_t)(i - n1) * 4);
    _Float16* dst = (i < n1) ? (w1h + (size_t)i * 4)
                             : (w2h + (size_t)(i - n1) * 4);
    float4 v = *(const float4*)src;
    half4_t h;
    h[0] = (_Float16)v.x; h[1] = (_Float16)v.y;
    h[2] = (_Float16)v.z; h[3] = (_Float16)v.w;
    *(half4_t*)dst = h;
  } else {
    const int c = bid - CONV_BLOCKS;          // chunk 0..127
    const int j = threadIdx.x * 4;            // 4 columns per thread
    const int t0 = c * CHR;
    float4 run = make_float4(0.f, 0.f, 0.f, 0.f);
    for (int t = t0; t < t0 + CHR; ++t) {
      float4 v = *(const float4*)&x[(size_t)t * HD + j];
      half4_t hx, hs;
      hx[0] = (_Float16)v.x;   hx[1] = (_Float16)v.y;
      hx[2] = (_Float16)v.z;   hx[3] = (_Float16)v.w;
      hs[0] = (_Float16)run.x; hs[1] = (_Float16)run.y;
      hs[2] = (_Float16)run.z; hs[3] = (_Float16)run.w;
      *(half4_t*)&A[(size_t)t * 2048 + j] = hx;
      *(half4_t*)&A[(size_t)t * 2048 + 1024 + j] = hs;
      run.x += v.x; run.y += v.y; run.z += v.z; run.w += v.w;
    }
    half4_t hxs;
    hxs[0] = (_Float16)run.x; hxs[1] = (_Float16)run.y;
    hxs[2] = (_Float16)run.z; hxs[3] = (_Float16)run.w;
    *(half4_t*)&xsum[(size_t)c * HD + j] = hxs;
  }
}

// ---------------- exclusive scan over NZ K-split partials + b1 -------------
__global__ void scan_part(const float* __restrict__ praw,
                          const float* __restrict__ b1,
                          float* __restrict__ pout) {
  int j = blockIdx.x * 256 + threadIdx.x;   // 0..3071
  const size_t SP = (size_t)NCH * NG;
  float run = b1[j];
  for (int c = 0; c < NCH; c += 8) {
    float v[8];
#pragma unroll
    for (int u = 0; u < 8; ++u) {
      size_t i0 = (size_t)(c + u) * NG + j;
      float s0 = praw[i0] + praw[i0 + SP];
      float s1 = praw[i0 + 2 * SP] + praw[i0 + 3 * SP];
      float s2 = praw[i0 + 4 * SP] + praw[i0 + 5 * SP];
      float s3 = praw[i0 + 6 * SP] + praw[i0 + 7 * SP];
      v[u] = (s0 + s1) + (s2 + s3);
    }
#pragma unroll
    for (int u = 0; u < 8; ++u) {
      pout[(size_t)(c + u) * NG + j] = run;
      run += v[u];
    }
  }
}

// ---------------- partGEMM: praw[z] = xsum @ W1b^T over K window z ---------
__global__ __launch_bounds__(256, 2)
void gemm_part(const _Float16* __restrict__ A, const _Float16* __restrict__ B,
               float* __restrict__ C) {
  __shared__ _Float16 As[128 * 32];
  __shared__ _Float16 Bs[128 * 32];

  const int tid = threadIdx.x;
  const int lane = tid & 63;
  const int wid = tid >> 6;
  const int wr = wid >> 1;
  const int wc = wid & 1;

  const int n0 = blockIdx.x * 128;
  const int koff = blockIdx.z * (1024 / NZ);

  const int srow = lane >> 2;
  const int scol = (lane & 3) << 3;

  const _Float16* gA = A + (size_t)(wid * 32 + srow) * 1024 + koff + scol;
  const _Float16* gB = B + (size_t)(n0 + wid * 32 + srow) * 2048 + koff + scol;
  _Float16* lA = As + (wid * 32) * 32;
  _Float16* lB = Bs + (wid * 32) * 32;

  f32x4_t acc[4][4] = {};

  const int fr = lane & 15;
  const int fk = (lane >> 4) << 3;

  for (int kk = 0; kk < 1024 / NZ; kk += 32) {
    gload_lds16(gA + kk,                    lA);
    gload_lds16(gA + kk + (size_t)16*1024,  lA + 16 * 32);
    gload_lds16(gB + kk,                    lB);
    gload_lds16(gB + kk + (size_t)16*2048,  lB + 16 * 32);
    __syncthreads();

    half8_t af[4], bf[4];
#pragma unroll
    for (int m = 0; m < 4; ++m)
      af[m] = *(const half8_t*)&As[(wr * 64 + m * 16 + fr) * 32 + fk];
#pragma unroll
    for (int n = 0; n < 4; ++n)
      bf[n] = *(const half8_t*)&Bs[(wc * 64 + n * 16 + fr) * 32 + fk];
#pragma unroll
    for (int m = 0; m < 4; ++m)
#pragma unroll
      for (int n = 0; n < 4; ++n)
        acc[m][n] = __builtin_amdgcn_mfma_f32_16x16x32_f16(af[m], bf[n],
                                                           acc[m][n], 0, 0, 0);
    __syncthreads();
  }

  float* Cz = C + (size_t)blockIdx.z * NCH * NG;
  const int crow = wr * 64 + ((lane >> 4) << 2);
  const int ccol = n0 + wc * 64 + fr;
#pragma unroll
  for (int m = 0; m < 4; ++m)
#pragma unroll
    for (int n = 0; n < 4; ++n) {
      const int col = ccol + n * 16;
#pragma unroll
      for (int r = 0; r < 4; ++r)
        Cz[(size_t)(crow + m * 16 + r) * NG + col] = acc[m][n][r];
    }
}

// ---------------- triple-buffered counted-vmcnt GEMM (proven R6) -----------
// MODE 1: outf[idx] = (acc + bias[col]) * (float)mulh[idx]   (GEMM2)
// MODE 2: g = acc + part[(row>>5)*NG + col]; gate epilogue   (GEMM1)
// SWZ 1: 1D grid, XCD-aware remap (NBX N-tiles, 4 M-tiles per XCD group)
#define BARX __builtin_amdgcn_s_barrier()
#define PR1 __builtin_amdgcn_s_setprio(1)
#define PR0 __builtin_amdgcn_s_setprio(0)
#define VM4 asm volatile("s_waitcnt vmcnt(4)" ::: "memory")

template <int NTILE, int MODE, int SWZ, int NBX>
__global__ __launch_bounds__(256, 3)
void gemm_t3(const _Float16* __restrict__ A, const _Float16* __restrict__ B,
             int N,
             const float* __restrict__ part, _Float16* __restrict__ igb,
             float* __restrict__ outf, _Float16* __restrict__ th,
             const float* __restrict__ bias, const _Float16* __restrict__ mulh) {
  constexpr int KS = NTILE * 32;
  __shared__ __align__(16) _Float16 sA[3][128 * 32];
  __shared__ __align__(16) _Float16 sB[3][128 * 32];

  const int tid = threadIdx.x;
  const int l = tid & 63;
  const int wid = tid >> 6;
  const int wr = wid >> 1;
  const int wc = wid & 1;

  int bx, by;
  if constexpr (SWZ) {
    // XCD b%8 round-robin: group 4 M-tiles per XCD, sweep N within group
    const int bid = blockIdx.x;
    const int xcd = bid & 7;
    const int q = bid >> 3;
    by = xcd * 4 + q / NBX;
    bx = q % NBX;
  } else {
    bx = blockIdx.x;
    by = blockIdx.y;
  }
  const int m0 = by * 128;
  const int n0 = bx * 128;

  const int srow = tid >> 2;
  const int schunk = (tid & 3) ^ ((tid >> 3) & 3);
  const _Float16* gA = A + (size_t)(m0 + srow) * KS + schunk * 8;
  const _Float16* gB = B + (size_t)(n0 + srow) * KS + schunk * 8;
  const int ldst = tid * 8;

#define STG(bn, kt) do {                                              \
    const int kk_ = (kt) * 32;                                        \
    gload_lds16(gA + kk_,           &sA[bn][ldst]);                   \
    gload_lds16(gA + kk_ + 64 * KS, &sA[bn][2048 + ldst]);            \
    gload_lds16(gB + kk_,           &sB[bn][ldst]);                   \
    gload_lds16(gB + kk_ + 64 * KS, &sB[bn][2048 + ldst]);            \
  } while (0)

  const int fr = l & 15;
  const int kidx = (((l >> 4) ^ ((l >> 1) & 3)) << 3);

  f32x4_t acc[4][4] = {};

#define BODY(kt, bc, bn) do {                                         \
    int ks_ = (kt) + 2; if (ks_ > NTILE - 1) ks_ = NTILE - 1;         \
    STG(bn, ks_);                                                     \
    half8_t af[4], bf[4];                                             \
    _Pragma("unroll")                                                 \
    for (int m = 0; m < 4; ++m)                                       \
      af[m] = *(const half8_t*)&sA[bc][(wr*64 + m*16 + fr)*32 + kidx];\
    _Pragma("unroll")                                                 \
    for (int n = 0; n < 4; ++n)                                       \
      bf[n] = *(const half8_t*)&sB[bc][(wc*64 + n*16 + fr)*32 + kidx];\
    PR1;                                                              \
    _Pragma("unroll")                                                 \
    for (int m = 0; m < 4; ++m)                                       \
      _Pragma("unroll")                                               \
      for (int n = 0; n < 4; ++n)                                     \
        acc[m][n] = __builtin_amdgcn_mfma_f32_16x16x32_f16(           \
            af[m], bf[n], acc[m][n], 0, 0, 0);                        \
    PR0;                                                              \
    VM4; BARX;                                                        \
  } while (0)

  STG(0, 0);
  STG(1, 1);
  VM4; BARX;

#pragma unroll 1
  for (int t3 = 0; t3 < NTILE / 3; ++t3) {
    const int kt = t3 * 3;
    BODY(kt,     0, 2);
    BODY(kt + 1, 1, 0);
    BODY(kt + 2, 2, 1);
  }
  if constexpr (NTILE % 3 >= 1) BODY(NTILE - NTILE % 3,     0, 2);
  if constexpr (NTILE % 3 >= 2) BODY(NTILE - NTILE % 3 + 1, 1, 0);

  // ---- epilogue ----
  const int crow = m0 + wr * 64 + ((l >> 4) << 2);
  const int ccol = n0 + wc * 64 + fr;

  float pv[2][4];
  if constexpr (MODE == 2) {
    const int cbase = crow >> 5;   // lane-uniform per 64-row wave span
#pragma unroll
    for (int h = 0; h < 2; ++h)
#pragma unroll
      for (int n = 0; n < 4; ++n)
        pv[h][n] = part[(size_t)(cbase + h) * NG + ccol + n * 16];
  }

#pragma unroll
  for (int m = 0; m < 4; ++m)
#pragma unroll
    for (int n = 0; n < 4; ++n) {
      const int col = ccol + n * 16;
#pragma unroll
      for (int r = 0; r < 4; ++r) {
        const int row = crow + m * 16 + r;
        const float v = acc[m][n][r];
        if (MODE == 1) {
          size_t idx = (size_t)row * N + col;
          outf[idx] = (v + bias[col]) * (float)mulh[idx];
        } else {
          float g = v + pv[m >> 1][n];
          if (col < 1024)
            igb[(size_t)row * HD + col] = (_Float16)sigmoidf_(g);
          else if (col < 2048)
            outf[(size_t)row * HD + (col - 1024)] = sigmoidf_(g);
          else
            th[(size_t)row * HD + (col - 2048)] = (_Float16)tanhf_(g);
        }
      }
    }
#undef STG
#undef BODY
}

// ---------------- launch ----------------
extern "C" void kernel_launch(void* const* d_in, const int* in_sizes, int n_in,
                              void* d_out, int out_size, void* d_ws, size_t ws_size,
                              hipStream_t stream) {
  const float* x  = (const float*)d_in[0];
  const float* W1 = (const float*)d_in[1];
  const float* b1 = (const float*)d_in[2];
  const float* W2 = (const float*)d_in[3];
  const float* b2 = (const float*)d_in[4];
  float* out0 = (float*)d_out;                          // fg [4096][1024]
  float* out1 = out0 + (size_t)S_SEQ * HD;              // hr [4096][1024]

  char* ws = (char*)d_ws;
  _Float16* Ah    = (_Float16*)(ws);                        // 16 MiB [4096][2048]
  _Float16* w1h   = (_Float16*)(ws + ((size_t)16 << 20));   // 12 MiB [3072][2048]
  _Float16* w2h   = (_Float16*)(ws + ((size_t)28 << 20));   //  2 MiB [1024][1024]
  _Float16* xsumh = (_Float16*)(ws + ((size_t)30 << 20));   // .25MiB [128][1024]
  float*    praw  = (float*)   (ws + ((size_t)31 << 20));   // 12 MiB [8][128][3072]
  float*    pout  = (float*)   (ws + ((size_t)43 << 20));   // 1.5MiB [128][3072]
  _Float16* igb   = (_Float16*)(ws + ((size_t)45 << 20));   //  8 MiB [4096][1024]
  _Float16* th    = (_Float16*)(ws + ((size_t)53 << 20));   //  8 MiB [4096][1024]

  prep<<<dim3(CONV_BLOCKS + 128), dim3(256), 0, stream>>>(
      W1, W2, w1h, w2h, x, Ah, xsumh);

  gemm_part<<<dim3(NG / 128, 1, NZ), dim3(256), 0, stream>>>(
      xsumh, w1h + 1024, praw);

  scan_part<<<dim3(NG / 256), dim3(256), 0, stream>>>(praw, b1, pout);

  // GEMM1: 768 blocks, XCD-swizzled 1D grid (8 XCD groups x 4 M-tiles x 24 N)
  gemm_t3<64, 2, 1, NG / 128><<<dim3(768), dim3(256), 0, stream>>>(
      Ah, w1h, NG, pout, igb, out0, th, nullptr, nullptr);

  // GEMM2: unchanged 2D grid
  gemm_t3<32, 1, 0, 0><<<dim3(HD / 128, S_SEQ / 128), dim3(256), 0, stream>>>(
      th, w2h, HD, nullptr, nullptr, out1, nullptr, b2, igb);
}